// Round 2
// baseline (291.070 us; speedup 1.0000x reference)
//
#include <hip/hip_runtime.h>
#include <hip/hip_fp16.h>
#include <math.h>

typedef _Float16 half_t;
typedef __attribute__((ext_vector_type(2))) _Float16 f16x2;
typedef __attribute__((ext_vector_type(4))) _Float16 f16x4;
typedef __attribute__((ext_vector_type(8))) _Float16 f16x8;
typedef __attribute__((ext_vector_type(4))) float f32x4;

#define BPTT 32
#define BSZ 32
#define NTOK 2000
#define NTOKP 2048
#define NINP 1024
#define NHID 256
#define TB 1024  /* BPTT*BSZ */
#define NH2 65536
#define TCH 16   /* t-steps per chunk */

// ---------------- conversion kernels ----------------

__global__ void cvt_split_pad_k(const float* __restrict__ in, half_t* __restrict__ hi,
                                half_t* __restrict__ lo, int cols) {
  int idx = blockIdx.x * 256 + threadIdx.x;  // rows*2048 total
  int r = idx >> 11, c = idx & 2047;
  float v = (c < cols) ? in[(size_t)r * cols + c] : 0.f;
  half_t h = (half_t)v;
  hi[idx] = h;
  lo[idx] = (half_t)(v - (float)h);
}

__global__ void cvt_half_k(const float* __restrict__ in, half_t* __restrict__ out, int n) {
  int idx = blockIdx.x * 256 + threadIdx.x;
  if (idx < n) out[idx] = (half_t)in[idx];
}

__global__ void cvt_pad_rows_k(const float* __restrict__ in, half_t* __restrict__ out,
                               int rows_valid) {
  int idx = blockIdx.x * 256 + threadIdx.x;  // 2048*256
  int r = idx >> 8, c = idx & 255;
  float v = (r < rows_valid) ? in[(size_t)r * 256 + c] : 0.f;
  out[idx] = (half_t)v;
}

// WWT[h*256+r][c] = wfef_w[r*256+c][h]  (fp16 output, h-major rows)
__global__ void permute_wfef_k(const float* __restrict__ wfef, half_t* __restrict__ wwt) {
  __shared__ float tile[32][33];
  int r = blockIdx.x, cb = blockIdx.y, hb = blockIdx.z;
  int tx = threadIdx.x, ty = threadIdx.y;
#pragma unroll
  for (int ii = 0; ii < 4; ii++) {
    int cl = ty + ii * 8;
    tile[cl][tx] = wfef[((size_t)(r * 256 + cb * 32 + cl)) * 256 + hb * 32 + tx];
  }
  __syncthreads();
#pragma unroll
  for (int ii = 0; ii < 4; ii++) {
    int hl = ty + ii * 8;
    wwt[((size_t)(hb * 32 + hl) * 256 + r) * 256 + cb * 32 + tx] = (half_t)tile[tx][hl];
  }
}

// ---------------- shared fp16 GEMM body, 128x128 tile, C = A @ B^T ----------------
// EP: 0 = store half (no bias)   [M-precompute]
//     1 = store half (acc+bias)  [obs]
//     2 = store f32 (no bias)    [V]
//     3 = store f32 (acc+bias) col guard gc<nvalid [decoder]
template <int EP>
__device__ __forceinline__ void gemm128_body(const half_t* __restrict__ A,
                                             const half_t* __restrict__ B,
                                             void* __restrict__ C,
                                             const float* __restrict__ bias, int K,
                                             int ldc, int nvalid, int row0, int col0) {
  __shared__ half_t As[128 * 32];
  __shared__ half_t Bs[128 * 32];
  const int tid = threadIdx.x;
  const int lane = tid & 63, wave = tid >> 6;
  const int wr = wave >> 1, wc = wave & 1;
  const int srow = tid >> 2, sseg = tid & 3;
  const size_t aoff = (size_t)(row0 + srow) * K + sseg * 8;
  const size_t boff = (size_t)(col0 + srow) * K + sseg * 8;
  const int fr = lane & 15, fq = lane >> 4;

  f32x4 acc[4][4];
#pragma unroll
  for (int m = 0; m < 4; m++)
#pragma unroll
    for (int n = 0; n < 4; n++) acc[m][n] = (f32x4)(0.0f);

  for (int k0 = 0; k0 < K; k0 += 32) {
    f16x8 a0 = *(const f16x8*)(A + aoff + k0);
    f16x8 a1 = *(const f16x8*)(A + aoff + (size_t)64 * K + k0);
    f16x8 b0 = *(const f16x8*)(B + boff + k0);
    f16x8 b1 = *(const f16x8*)(B + boff + (size_t)64 * K + k0);
    __syncthreads();
    *(f16x8*)(As + srow * 32 + sseg * 8) = a0;
    *(f16x8*)(As + (srow + 64) * 32 + sseg * 8) = a1;
    *(f16x8*)(Bs + srow * 32 + sseg * 8) = b0;
    *(f16x8*)(Bs + (srow + 64) * 32 + sseg * 8) = b1;
    __syncthreads();
    f16x8 af[4], bf[4];
#pragma unroll
    for (int m = 0; m < 4; m++)
      af[m] = *(const f16x8*)(As + (wr * 64 + m * 16 + fr) * 32 + fq * 8);
#pragma unroll
    for (int n = 0; n < 4; n++)
      bf[n] = *(const f16x8*)(Bs + (wc * 64 + n * 16 + fr) * 32 + fq * 8);
#pragma unroll
    for (int m = 0; m < 4; m++)
#pragma unroll
      for (int n = 0; n < 4; n++)
        acc[m][n] = __builtin_amdgcn_mfma_f32_16x16x32_f16(af[m], bf[n], acc[m][n], 0, 0, 0);
  }

#pragma unroll
  for (int m = 0; m < 4; m++) {
#pragma unroll
    for (int n = 0; n < 4; n++) {
#pragma unroll
      for (int j = 0; j < 4; j++) {
        int gr = row0 + wr * 64 + m * 16 + fq * 4 + j;
        int gc = col0 + wc * 64 + n * 16 + fr;
        float v = acc[m][n][j];
        if (EP == 0) {
          ((half_t*)C)[(size_t)gr * ldc + gc] = (half_t)v;
        } else if (EP == 1) {
          ((half_t*)C)[(size_t)gr * ldc + gc] = (half_t)(v + bias[gc]);
        } else if (EP == 2) {
          ((float*)C)[(size_t)gr * ldc + gc] = v;
        } else {
          if (gc < nvalid) ((float*)C)[(size_t)gr * ldc + gc] = v + bias[gc];
        }
      }
    }
  }
}

template <int EP>
__global__ __launch_bounds__(256) void gemm128_k(const half_t* __restrict__ A,
                                                 const half_t* __restrict__ B,
                                                 void* __restrict__ C,
                                                 const float* __restrict__ bias, int K,
                                                 int ldc, int nvalid) {
  gemm128_body<EP>(A, B, C, bias, K, ldc, nvalid, blockIdx.x * 128, blockIdx.y * 128);
}

// M-GEMM chunk: 2048 linear blocks, XCD-swizzled so all 4 row-blocks sharing a
// WWT column-slab land on the same XCD (slab becomes L2-resident; WWT read
// ~once from HBM instead of 4x). K=256, ldc=NH2, 512 rows per chunk.
__global__ __launch_bounds__(256) void gemm_m_k(const half_t* __restrict__ A,
                                                const half_t* __restrict__ B,
                                                half_t* __restrict__ C) {
  int id = blockIdx.x;            // 0..2047
  int c = id & 7, k = id >> 3;    // xcd (round-robin), per-xcd index
  int bx = k & 3, by = c + 8 * (k >> 2);
  gemm128_body<0>(A, B, (void*)C, nullptr, 256, NH2, 0, bx * 128, by * 128);
}

// ---------------- split-precision RBF GEMM (3-term hi/lo), 128x64 tile ----------------
// 128 linear blocks, XCD-swizzled by row-slab (A hi+lo slab 2MB fits one L2).
__global__ __launch_bounds__(256) void gemm1_split3_k(
    const half_t* __restrict__ Ahi, const half_t* __restrict__ Alo,
    const half_t* __restrict__ Bhi, const half_t* __restrict__ Blo,
    const float* __restrict__ bias, half_t* __restrict__ C, int K, int ldc) {
  __shared__ half_t Ash[128 * 32];
  __shared__ half_t Asl[128 * 32];
  __shared__ half_t Bsh[64 * 32];
  __shared__ half_t Bsl[64 * 32];
  const int tid = threadIdx.x;
  const int bx = blockIdx.x & 7, by = blockIdx.x >> 3;  // XCD swizzle
  const int lane = tid & 63, wave = tid >> 6;
  const int wr = wave >> 1, wc = wave & 1;
  const int row0 = bx * 128, col0 = by * 64;
  const int srow = tid >> 2, sseg = tid & 3;
  const size_t aoff = (size_t)(row0 + srow) * K + sseg * 8;
  const size_t boff = (size_t)(col0 + srow) * K + sseg * 8;
  const int fr = lane & 15, fq = lane >> 4;

  f32x4 acc[4][2];
#pragma unroll
  for (int m = 0; m < 4; m++)
#pragma unroll
    for (int n = 0; n < 2; n++) acc[m][n] = (f32x4)(0.0f);

  for (int k0 = 0; k0 < K; k0 += 32) {
    f16x8 ah0 = *(const f16x8*)(Ahi + aoff + k0);
    f16x8 ah1 = *(const f16x8*)(Ahi + aoff + (size_t)64 * K + k0);
    f16x8 al0 = *(const f16x8*)(Alo + aoff + k0);
    f16x8 al1 = *(const f16x8*)(Alo + aoff + (size_t)64 * K + k0);
    f16x8 bh0 = *(const f16x8*)(Bhi + boff + k0);
    f16x8 bl0 = *(const f16x8*)(Blo + boff + k0);
    __syncthreads();
    *(f16x8*)(Ash + srow * 32 + sseg * 8) = ah0;
    *(f16x8*)(Ash + (srow + 64) * 32 + sseg * 8) = ah1;
    *(f16x8*)(Asl + srow * 32 + sseg * 8) = al0;
    *(f16x8*)(Asl + (srow + 64) * 32 + sseg * 8) = al1;
    *(f16x8*)(Bsh + srow * 32 + sseg * 8) = bh0;
    *(f16x8*)(Bsl + srow * 32 + sseg * 8) = bl0;
    __syncthreads();
    f16x8 afh[4], afl[4], bfh[2], bfl[2];
#pragma unroll
    for (int m = 0; m < 4; m++) {
      afh[m] = *(const f16x8*)(Ash + (wr * 64 + m * 16 + fr) * 32 + fq * 8);
      afl[m] = *(const f16x8*)(Asl + (wr * 64 + m * 16 + fr) * 32 + fq * 8);
    }
#pragma unroll
    for (int n = 0; n < 2; n++) {
      bfh[n] = *(const f16x8*)(Bsh + (wc * 32 + n * 16 + fr) * 32 + fq * 8);
      bfl[n] = *(const f16x8*)(Bsl + (wc * 32 + n * 16 + fr) * 32 + fq * 8);
    }
#pragma unroll
    for (int m = 0; m < 4; m++)
#pragma unroll
      for (int n = 0; n < 2; n++) {
        acc[m][n] = __builtin_amdgcn_mfma_f32_16x16x32_f16(afh[m], bfh[n], acc[m][n], 0, 0, 0);
        acc[m][n] = __builtin_amdgcn_mfma_f32_16x16x32_f16(afl[m], bfh[n], acc[m][n], 0, 0, 0);
        acc[m][n] = __builtin_amdgcn_mfma_f32_16x16x32_f16(afh[m], bfl[n], acc[m][n], 0, 0, 0);
      }
  }

  const float RBF_SCALE = 0.04419417382415922f;  // sqrt(2)/sqrt(1024)
#pragma unroll
  for (int m = 0; m < 4; m++) {
#pragma unroll
    for (int n = 0; n < 2; n++) {
#pragma unroll
      for (int j = 0; j < 4; j++) {
        int gr = row0 + wr * 64 + m * 16 + fq * 4 + j;
        int gc = col0 + wc * 32 + n * 16 + fr;
        float v = acc[m][n][j] + bias[gc];
        C[(size_t)gr * ldc + gc] = (half_t)(cosf(v) * RBF_SCALE);
      }
    }
  }
}

// ---------------- sequential scan segment: TCH steps, 32 blocks ----------------
// bn_pre[r] = sum_h b[h]*Mc[tb][h*256+r] + V[t][r]; bn = bn_pre/||bn_pre||
// wave = h-group (16 h), lane = 4 r's. V preloaded to LDS; b carried as fp16
// pairs in LDS (wave-uniform broadcast reads); fp16xfp16+fp32 MACs (fma_mix).
__global__ __launch_bounds__(1024, 4) void scan_seg_k(
    const half_t* __restrict__ Mc, const float* __restrict__ V, int t0,
    const float* __restrict__ bin, float* __restrict__ bstate,
    half_t* __restrict__ BN, float* __restrict__ bfinal) {
  __shared__ float Vs[TCH][256];
  __shared__ float partial[16][260];
  __shared__ __align__(16) unsigned bh2[128];
  __shared__ float red[4];
  const int b = blockIdx.x, tid = threadIdx.x;
  const int hh = tid >> 6;  // wave id = h-group (16 h each)
  const int rv = tid & 63;  // 4 r's each

  // preload V for this segment (one float4 per thread)
  *(f32x4*)&Vs[hh][rv * 4] =
      *(const f32x4*)(V + ((size_t)(t0 + hh) * 32 + b) * 256 + rv * 4);
  // init b as packed fp16 pairs
  if (tid < 128) {
    const float* bs = bin + b * 256 + tid * 2;
    union { f16x2 h; unsigned u; } z;
    z.h[0] = (half_t)bs[0];
    z.h[1] = (half_t)bs[1];
    bh2[tid] = z.u;
  }

  const half_t* mbase = Mc + (size_t)b * NH2 + (hh * 16) * 256 + rv * 4;
  f16x4 cur[16], nxt[16];
#pragma unroll
  for (int k = 0; k < 16; k++) cur[k] = *(const f16x4*)(mbase + k * 256);
  __syncthreads();

  for (int tt = 0; tt < TCH; tt++) {
    // prefetch next step's M tile
    const int tn = (tt < TCH - 1) ? tt + 1 : TCH - 1;
    const half_t* mb2 = mbase + (size_t)tn * 32 * NH2;
#pragma unroll
    for (int k = 0; k < 16; k++) nxt[k] = *(const f16x4*)(mb2 + k * 256);

    // wave-uniform broadcast read of this wave's 16 b-halves
    uint4 bq0 = *(const uint4*)&bh2[hh * 8];
    uint4 bq1 = *(const uint4*)&bh2[hh * 8 + 4];
    half_t hv[16];
    *(uint4*)&hv[0] = bq0;
    *(uint4*)&hv[8] = bq1;

    float a0 = 0.f, a1 = 0.f, a2 = 0.f, a3 = 0.f;
#pragma unroll
    for (int k = 0; k < 16; k++) {
      a0 += (float)cur[k][0] * (float)hv[k];
      a1 += (float)cur[k][1] * (float)hv[k];
      a2 += (float)cur[k][2] * (float)hv[k];
      a3 += (float)cur[k][3] * (float)hv[k];
    }
    f32x4 av = {a0, a1, a2, a3};
    *(f32x4*)&partial[hh][rv * 4] = av;
    __syncthreads();  // B1: partial ready

    float s = 0.f;
    if (tid < 256) {
#pragma unroll
      for (int g = 0; g < 16; g++) s += partial[g][tid];
      s += Vs[tt][tid];
      float sq = s * s;
#pragma unroll
      for (int o = 32; o > 0; o >>= 1) sq += __shfl_xor(sq, o);
      if ((tid & 63) == 0) red[tid >> 6] = sq;
    }
    __syncthreads();  // B2: red ready
    if (tid < 256) {
      float sumsq = red[0] + red[1] + red[2] + red[3];
      float bnv = s / sqrtf(sumsq);
      float bnv_hi = __shfl_down(bnv, 1);
      if (!(tid & 1)) {
        union { f16x2 h; unsigned u; } z;
        z.h[0] = (half_t)bnv;
        z.h[1] = (half_t)bnv_hi;
        bh2[tid >> 1] = z.u;
        *(unsigned*)(BN + ((size_t)(t0 + tt) * 32 + b) * 256 + tid) = z.u;
      }
      if (tt == TCH - 1) bstate[b * 256 + tid] = bnv;
      if (t0 + tt == BPTT - 1) bfinal[b * 256 + tid] = bnv;
    }
    __syncthreads();  // B3: bh2 ready for next step
#pragma unroll
    for (int k = 0; k < 16; k++) cur[k] = nxt[k];
  }
}

// ---------------- launch ----------------

extern "C" void kernel_launch(void* const* d_in, const int* in_sizes, int n_in,
                              void* d_out, int out_size, void* d_ws, size_t ws_size,
                              hipStream_t stream) {
  const float* input = (const float*)d_in[0];
  const float* b0 = (const float*)d_in[1];
  const float* RBF_w = (const float*)d_in[2];
  const float* RBF_b = (const float*)d_in[3];
  const float* emb_w = (const float*)d_in[4];
  const float* emb_b = (const float*)d_in[5];
  const float* wfef_w = (const float*)d_in[6];
  const float* wfef_b = (const float*)d_in[7];
  const float* dec_w = (const float*)d_in[8];
  const float* dec_b = (const float*)d_in[9];

  char* ws = (char*)d_ws;
  size_t off = 0;
  auto alloc = [&](size_t bytes) {
    void* p = ws + off;
    off += (bytes + 255) & ~(size_t)255;
    return p;
  };
  half_t* A1hi = (half_t*)alloc((size_t)TB * NTOKP * 2);
  half_t* A1lo = (half_t*)alloc((size_t)TB * NTOKP * 2);
  half_t* B1hi = (half_t*)alloc((size_t)NINP * NTOKP * 2);
  half_t* B1lo = (half_t*)alloc((size_t)NINP * NTOKP * 2);
  half_t* encA = (half_t*)alloc((size_t)TB * NINP * 2);
  half_t* B2 = (half_t*)alloc((size_t)NHID * NINP * 2);
  half_t* obsA = (half_t*)alloc((size_t)TB * NHID * 2);
  half_t* WBh = (half_t*)alloc((size_t)NHID * NHID * 2);
  half_t* B4 = (half_t*)alloc((size_t)2048 * NHID * 2);
  float* Vbuf = (float*)alloc((size_t)TB * NHID * 4);
  half_t* BN = (half_t*)alloc((size_t)TB * NHID * 2);
  float* bstate = (float*)alloc((size_t)BSZ * NHID * 4);
  half_t* WWT = (half_t*)alloc((size_t)NH2 * NHID * 2);
  half_t* Mmat = (half_t*)alloc((size_t)TB * NH2 * 2);
  if (off > ws_size) return;  // workspace too small: fail loudly

  float* outp = (float*)d_out;
  float* bfinal = outp + (size_t)TB * NTOK;

  // conversions
  cvt_split_pad_k<<<(TB * NTOKP) / 256, 256, 0, stream>>>(input, A1hi, A1lo, NTOK);
  cvt_split_pad_k<<<(NINP * NTOKP) / 256, 256, 0, stream>>>(RBF_w, B1hi, B1lo, NTOK);
  cvt_half_k<<<(NHID * NINP) / 256, 256, 0, stream>>>(emb_w, B2, NHID * NINP);
  cvt_half_k<<<(NHID * NHID) / 256, 256, 0, stream>>>(wfef_b, WBh, NHID * NHID);
  cvt_pad_rows_k<<<(2048 * NHID) / 256, 256, 0, stream>>>(dec_w, B4, NTOK);
  permute_wfef_k<<<dim3(256, 8, 8), dim3(32, 8), 0, stream>>>(wfef_w, WWT);

  // encoded = cos(input @ RBF_w.T + RBF_b) * scale   [split precision, XCD-swizzled]
  gemm1_split3_k<<<128, 256, 0, stream>>>(A1hi, A1lo, B1hi, B1lo, RBF_b, encA, NTOKP,
                                          NINP);
  // obs = encoded @ emb_w.T + emb_b
  gemm128_k<1><<<dim3(8, 2), 256, 0, stream>>>(encA, B2, obsA, emb_b, NINP, NHID, 0);
  // V = obs @ reshape(wfef_b)^T
  gemm128_k<2><<<dim3(8, 2), 256, 0, stream>>>(obsA, WBh, Vbuf, nullptr, NHID, NHID, 0);

  // chunked: M-GEMM (t-chunk) then scan segment while chunk is L3-hot
  for (int tc = 0; tc < BPTT / TCH; tc++) {
    const int t0 = tc * TCH;
    gemm_m_k<<<2048, 256, 0, stream>>>(obsA + (size_t)t0 * 32 * NHID, WWT,
                                       Mmat + (size_t)t0 * 32 * NH2);
    scan_seg_k<<<32, 1024, 0, stream>>>(Mmat + (size_t)t0 * 32 * NH2, Vbuf, t0,
                                        (t0 == 0) ? b0 : bstate, bstate, BN, bfinal);
  }

  // outputs = BN @ dec_w.T + dec_b
  gemm128_k<3><<<dim3(8, 16), 256, 0, stream>>>(BN, B4, outp, dec_b, NHID, NTOK, NTOK);
}

// Round 3
// 261.121 us; speedup vs baseline: 1.1147x; 1.1147x over previous
//
#include <hip/hip_runtime.h>
#include <hip/hip_fp16.h>
#include <math.h>

typedef _Float16 half_t;
typedef __attribute__((ext_vector_type(2))) _Float16 f16x2;
typedef __attribute__((ext_vector_type(4))) _Float16 f16x4;
typedef __attribute__((ext_vector_type(8))) _Float16 f16x8;
typedef __attribute__((ext_vector_type(4))) float f32x4;

#define BPTT 32
#define BSZ 32
#define NTOK 2000
#define NTOKP 2048
#define NINP 1024
#define NHID 256
#define TB 1024  /* BPTT*BSZ */
#define NH2 65536
#define TCH 16   /* t-steps per chunk */

// LDS bank-quad swizzle for 32-half (64B) rows: spreads stride-64B row access
// across all 8 b128 bank-quads (2-way max = free). Bijective (bit5 of idx is
// recoverable since mask source bits [7:5] are partly above the modified bits
// and bit7 is untouched). Apply identically on write and read.
__device__ __forceinline__ int swz(int row, int hoff) {
  return (row * 32 + hoff) ^ ((row & 7) << 3);
}

// ---------------- conversion kernels ----------------

__global__ void cvt_split_pad_k(const float* __restrict__ in, half_t* __restrict__ hi,
                                half_t* __restrict__ lo, int cols) {
  int idx = blockIdx.x * 256 + threadIdx.x;  // rows*2048 total
  int r = idx >> 11, c = idx & 2047;
  float v = (c < cols) ? in[(size_t)r * cols + c] : 0.f;
  half_t h = (half_t)v;
  hi[idx] = h;
  lo[idx] = (half_t)(v - (float)h);
}

__global__ void cvt_half_k(const float* __restrict__ in, half_t* __restrict__ out, int n) {
  int idx = blockIdx.x * 256 + threadIdx.x;
  if (idx < n) out[idx] = (half_t)in[idx];
}

__global__ void cvt_pad_rows_k(const float* __restrict__ in, half_t* __restrict__ out,
                               int rows_valid) {
  int idx = blockIdx.x * 256 + threadIdx.x;  // 2048*256
  int r = idx >> 8, c = idx & 255;
  float v = (r < rows_valid) ? in[(size_t)r * 256 + c] : 0.f;
  out[idx] = (half_t)v;
}

// WWT[h*256+r][c] = wfef_w[r*256+c][h]  (fp16 output, h-major rows)
__global__ void permute_wfef_k(const float* __restrict__ wfef, half_t* __restrict__ wwt) {
  __shared__ float tile[32][33];
  int r = blockIdx.x, cb = blockIdx.y, hb = blockIdx.z;
  int tx = threadIdx.x, ty = threadIdx.y;
#pragma unroll
  for (int ii = 0; ii < 4; ii++) {
    int cl = ty + ii * 8;
    tile[cl][tx] = wfef[((size_t)(r * 256 + cb * 32 + cl)) * 256 + hb * 32 + tx];
  }
  __syncthreads();
#pragma unroll
  for (int ii = 0; ii < 4; ii++) {
    int hl = ty + ii * 8;
    wwt[((size_t)(hb * 32 + hl) * 256 + r) * 256 + cb * 32 + tx] = (half_t)tile[tx][hl];
  }
}

// ---------------- shared fp16 GEMM body, 128x128 tile, C = A @ B^T ----------------
// EP: 0 = store half (no bias)   [M-precompute]
//     1 = store half (acc+bias)  [obs]
//     2 = store f32 (no bias)    [V]
//     3 = store f32 (acc+bias) col guard gc<nvalid [decoder]
template <int EP>
__device__ __forceinline__ void gemm128_body(const half_t* __restrict__ A,
                                             const half_t* __restrict__ B,
                                             void* __restrict__ C,
                                             const float* __restrict__ bias, int K,
                                             int ldc, int nvalid, int row0, int col0) {
  __shared__ half_t As[128 * 32];
  __shared__ half_t Bs[128 * 32];
  const int tid = threadIdx.x;
  const int lane = tid & 63, wave = tid >> 6;
  const int wr = wave >> 1, wc = wave & 1;
  const int srow = tid >> 2, sseg = tid & 3;
  const size_t aoff = (size_t)(row0 + srow) * K + sseg * 8;
  const size_t boff = (size_t)(col0 + srow) * K + sseg * 8;
  const int fr = lane & 15, fq = lane >> 4;

  f32x4 acc[4][4];
#pragma unroll
  for (int m = 0; m < 4; m++)
#pragma unroll
    for (int n = 0; n < 4; n++) acc[m][n] = (f32x4)(0.0f);

  for (int k0 = 0; k0 < K; k0 += 32) {
    f16x8 a0 = *(const f16x8*)(A + aoff + k0);
    f16x8 a1 = *(const f16x8*)(A + aoff + (size_t)64 * K + k0);
    f16x8 b0 = *(const f16x8*)(B + boff + k0);
    f16x8 b1 = *(const f16x8*)(B + boff + (size_t)64 * K + k0);
    __syncthreads();
    *(f16x8*)(As + swz(srow, sseg * 8)) = a0;
    *(f16x8*)(As + swz(srow + 64, sseg * 8)) = a1;
    *(f16x8*)(Bs + swz(srow, sseg * 8)) = b0;
    *(f16x8*)(Bs + swz(srow + 64, sseg * 8)) = b1;
    __syncthreads();
    f16x8 af[4], bf[4];
#pragma unroll
    for (int m = 0; m < 4; m++)
      af[m] = *(const f16x8*)(As + swz(wr * 64 + m * 16 + fr, fq * 8));
#pragma unroll
    for (int n = 0; n < 4; n++)
      bf[n] = *(const f16x8*)(Bs + swz(wc * 64 + n * 16 + fr, fq * 8));
#pragma unroll
    for (int m = 0; m < 4; m++)
#pragma unroll
      for (int n = 0; n < 4; n++)
        acc[m][n] = __builtin_amdgcn_mfma_f32_16x16x32_f16(af[m], bf[n], acc[m][n], 0, 0, 0);
  }

#pragma unroll
  for (int m = 0; m < 4; m++) {
#pragma unroll
    for (int n = 0; n < 4; n++) {
#pragma unroll
      for (int j = 0; j < 4; j++) {
        int gr = row0 + wr * 64 + m * 16 + fq * 4 + j;
        int gc = col0 + wc * 64 + n * 16 + fr;
        float v = acc[m][n][j];
        if (EP == 0) {
          ((half_t*)C)[(size_t)gr * ldc + gc] = (half_t)v;
        } else if (EP == 1) {
          ((half_t*)C)[(size_t)gr * ldc + gc] = (half_t)(v + bias[gc]);
        } else if (EP == 2) {
          ((float*)C)[(size_t)gr * ldc + gc] = v;
        } else {
          if (gc < nvalid) ((float*)C)[(size_t)gr * ldc + gc] = v + bias[gc];
        }
      }
    }
  }
}

template <int EP>
__global__ __launch_bounds__(256) void gemm128_k(const half_t* __restrict__ A,
                                                 const half_t* __restrict__ B,
                                                 void* __restrict__ C,
                                                 const float* __restrict__ bias, int K,
                                                 int ldc, int nvalid) {
  gemm128_body<EP>(A, B, C, bias, K, ldc, nvalid, blockIdx.x * 128, blockIdx.y * 128);
}

// M-GEMM chunk: 2048 linear blocks, XCD-swizzled so all 4 row-blocks sharing a
// WWT column-slab land on the same XCD. K=256, ldc=NH2, 512 rows per chunk.
__global__ __launch_bounds__(256) void gemm_m_k(const half_t* __restrict__ A,
                                                const half_t* __restrict__ B,
                                                half_t* __restrict__ C) {
  int id = blockIdx.x;            // 0..2047
  int c = id & 7, k = id >> 3;    // xcd (round-robin), per-xcd index
  int bx = k & 3, by = c + 8 * (k >> 2);
  gemm128_body<0>(A, B, (void*)C, nullptr, 256, NH2, 0, bx * 128, by * 128);
}

// ---------------- split-precision RBF GEMM (3-term hi/lo), split-K=4 ----------------
// 512 blocks: id = {kp(2b) | bx(3b) | by(4b)} -> P[kp][1024][1024] f32 partials.
__global__ __launch_bounds__(256) void gemm1_splitk_k(
    const half_t* __restrict__ Ahi, const half_t* __restrict__ Alo,
    const half_t* __restrict__ Bhi, const half_t* __restrict__ Blo,
    float* __restrict__ P) {
  __shared__ half_t Ash[128 * 32];
  __shared__ half_t Asl[128 * 32];
  __shared__ half_t Bsh[64 * 32];
  __shared__ half_t Bsl[64 * 32];
  const int id = blockIdx.x;
  const int kp = id & 3, r2 = id >> 2;
  const int bx = r2 & 7, by = r2 >> 3;
  const int row0 = bx * 128, col0 = by * 64, koff = kp * 512;
  const int tid = threadIdx.x;
  const int lane = tid & 63, wave = tid >> 6;
  const int wr = wave >> 1, wc = wave & 1;  // waves 2x2; wave tile 64x32
  const int srow = tid >> 2, sseg = tid & 3;
  const size_t aoff = (size_t)(row0 + srow) * NTOKP + koff + sseg * 8;
  const size_t boff = (size_t)(col0 + srow) * NTOKP + koff + sseg * 8;
  const int fr = lane & 15, fq = lane >> 4;

  f32x4 acc[4][2];
#pragma unroll
  for (int m = 0; m < 4; m++)
#pragma unroll
    for (int n = 0; n < 2; n++) acc[m][n] = (f32x4)(0.0f);

  for (int k0 = 0; k0 < 512; k0 += 32) {
    f16x8 ah0 = *(const f16x8*)(Ahi + aoff + k0);
    f16x8 ah1 = *(const f16x8*)(Ahi + aoff + (size_t)64 * NTOKP + k0);
    f16x8 al0 = *(const f16x8*)(Alo + aoff + k0);
    f16x8 al1 = *(const f16x8*)(Alo + aoff + (size_t)64 * NTOKP + k0);
    f16x8 bh0 = *(const f16x8*)(Bhi + boff + k0);
    f16x8 bl0 = *(const f16x8*)(Blo + boff + k0);
    __syncthreads();
    *(f16x8*)(Ash + swz(srow, sseg * 8)) = ah0;
    *(f16x8*)(Ash + swz(srow + 64, sseg * 8)) = ah1;
    *(f16x8*)(Asl + swz(srow, sseg * 8)) = al0;
    *(f16x8*)(Asl + swz(srow + 64, sseg * 8)) = al1;
    *(f16x8*)(Bsh + swz(srow, sseg * 8)) = bh0;
    *(f16x8*)(Bsl + swz(srow, sseg * 8)) = bl0;
    __syncthreads();
    f16x8 afh[4], afl[4], bfh[2], bfl[2];
#pragma unroll
    for (int m = 0; m < 4; m++) {
      afh[m] = *(const f16x8*)(Ash + swz(wr * 64 + m * 16 + fr, fq * 8));
      afl[m] = *(const f16x8*)(Asl + swz(wr * 64 + m * 16 + fr, fq * 8));
    }
#pragma unroll
    for (int n = 0; n < 2; n++) {
      bfh[n] = *(const f16x8*)(Bsh + swz(wc * 32 + n * 16 + fr, fq * 8));
      bfl[n] = *(const f16x8*)(Bsl + swz(wc * 32 + n * 16 + fr, fq * 8));
    }
#pragma unroll
    for (int m = 0; m < 4; m++)
#pragma unroll
      for (int n = 0; n < 2; n++) {
        acc[m][n] = __builtin_amdgcn_mfma_f32_16x16x32_f16(afh[m], bfh[n], acc[m][n], 0, 0, 0);
        acc[m][n] = __builtin_amdgcn_mfma_f32_16x16x32_f16(afl[m], bfh[n], acc[m][n], 0, 0, 0);
        acc[m][n] = __builtin_amdgcn_mfma_f32_16x16x32_f16(afh[m], bfl[n], acc[m][n], 0, 0, 0);
      }
  }

  float* Pk = P + (size_t)kp * (NINP * (size_t)TB);
#pragma unroll
  for (int m = 0; m < 4; m++) {
#pragma unroll
    for (int n = 0; n < 2; n++) {
#pragma unroll
      for (int j = 0; j < 4; j++) {
        int gr = row0 + wr * 64 + m * 16 + fq * 4 + j;
        int gc = col0 + wc * 32 + n * 16 + fr;
        Pk[(size_t)gr * NINP + gc] = acc[m][n][j];
      }
    }
  }
}

// combine split-K partials: encA = f16(cos(sum_kp P + bias) * scale)
__global__ void rbf_combine_k(const float* __restrict__ P, const float* __restrict__ bias,
                              half_t* __restrict__ C) {
  int idx = blockIdx.x * 256 + threadIdx.x;  // over TB*NINP/4
  int e0 = idx * 4;
  int col = e0 & (NINP - 1);
  f32x4 s = *(const f32x4*)(P + e0);
  s += *(const f32x4*)(P + (size_t)1 * TB * NINP + e0);
  s += *(const f32x4*)(P + (size_t)2 * TB * NINP + e0);
  s += *(const f32x4*)(P + (size_t)3 * TB * NINP + e0);
  const float RBF_SCALE = 0.04419417382415922f;  // sqrt(2)/sqrt(1024)
  f16x4 o;
#pragma unroll
  for (int j = 0; j < 4; j++) o[j] = (half_t)(cosf(s[j] + bias[col + j]) * RBF_SCALE);
  *(f16x4*)(C + e0) = o;
}

// ---------------- sequential scan segment: TCH steps, 32 blocks ----------------
__global__ __launch_bounds__(1024, 4) void scan_seg_k(
    const half_t* __restrict__ Mc, const float* __restrict__ V, int t0,
    const float* __restrict__ bin, float* __restrict__ bstate,
    half_t* __restrict__ BN, float* __restrict__ bfinal) {
  __shared__ float Vs[TCH][256];
  __shared__ float partial[16][260];
  __shared__ __align__(16) unsigned bh2[128];
  __shared__ float red[4];
  const int b = blockIdx.x, tid = threadIdx.x;
  const int hh = tid >> 6;  // wave id = h-group (16 h each)
  const int rv = tid & 63;  // 4 r's each

  *(f32x4*)&Vs[hh][rv * 4] =
      *(const f32x4*)(V + ((size_t)(t0 + hh) * 32 + b) * 256 + rv * 4);
  if (tid < 128) {
    const float* bs = bin + b * 256 + tid * 2;
    union { f16x2 h; unsigned u; } z;
    z.h[0] = (half_t)bs[0];
    z.h[1] = (half_t)bs[1];
    bh2[tid] = z.u;
  }

  const half_t* mbase = Mc + (size_t)b * NH2 + (hh * 16) * 256 + rv * 4;
  f16x4 cur[16], nxt[16];
#pragma unroll
  for (int k = 0; k < 16; k++) cur[k] = *(const f16x4*)(mbase + k * 256);
  __syncthreads();

  for (int tt = 0; tt < TCH; tt++) {
    const int tn = (tt < TCH - 1) ? tt + 1 : TCH - 1;
    const half_t* mb2 = mbase + (size_t)tn * 32 * NH2;
#pragma unroll
    for (int k = 0; k < 16; k++) nxt[k] = *(const f16x4*)(mb2 + k * 256);

    uint4 bq0 = *(const uint4*)&bh2[hh * 8];
    uint4 bq1 = *(const uint4*)&bh2[hh * 8 + 4];
    half_t hv[16];
    *(uint4*)&hv[0] = bq0;
    *(uint4*)&hv[8] = bq1;

    float a0 = 0.f, a1 = 0.f, a2 = 0.f, a3 = 0.f;
#pragma unroll
    for (int k = 0; k < 16; k++) {
      a0 += (float)cur[k][0] * (float)hv[k];
      a1 += (float)cur[k][1] * (float)hv[k];
      a2 += (float)cur[k][2] * (float)hv[k];
      a3 += (float)cur[k][3] * (float)hv[k];
    }
    f32x4 av = {a0, a1, a2, a3};
    *(f32x4*)&partial[hh][rv * 4] = av;
    __syncthreads();  // B1: partial ready

    float s = 0.f;
    if (tid < 256) {
#pragma unroll
      for (int g = 0; g < 16; g++) s += partial[g][tid];
      s += Vs[tt][tid];
      float sq = s * s;
#pragma unroll
      for (int o = 32; o > 0; o >>= 1) sq += __shfl_xor(sq, o);
      if ((tid & 63) == 0) red[tid >> 6] = sq;
    }
    __syncthreads();  // B2: red ready
    if (tid < 256) {
      float sumsq = red[0] + red[1] + red[2] + red[3];
      float bnv = s / sqrtf(sumsq);
      float bnv_hi = __shfl_down(bnv, 1);
      if (!(tid & 1)) {
        union { f16x2 h; unsigned u; } z;
        z.h[0] = (half_t)bnv;
        z.h[1] = (half_t)bnv_hi;
        bh2[tid >> 1] = z.u;
        *(unsigned*)(BN + ((size_t)(t0 + tt) * 32 + b) * 256 + tid) = z.u;
      }
      if (tt == TCH - 1) bstate[b * 256 + tid] = bnv;
      if (t0 + tt == BPTT - 1) bfinal[b * 256 + tid] = bnv;
    }
    __syncthreads();  // B3: bh2 ready for next step
#pragma unroll
    for (int k = 0; k < 16; k++) cur[k] = nxt[k];
  }
}

// ---------------- launch ----------------

extern "C" void kernel_launch(void* const* d_in, const int* in_sizes, int n_in,
                              void* d_out, int out_size, void* d_ws, size_t ws_size,
                              hipStream_t stream) {
  const float* input = (const float*)d_in[0];
  const float* b0 = (const float*)d_in[1];
  const float* RBF_w = (const float*)d_in[2];
  const float* RBF_b = (const float*)d_in[3];
  const float* emb_w = (const float*)d_in[4];
  const float* emb_b = (const float*)d_in[5];
  const float* wfef_w = (const float*)d_in[6];
  const float* wfef_b = (const float*)d_in[7];
  const float* dec_w = (const float*)d_in[8];
  const float* dec_b = (const float*)d_in[9];

  char* ws = (char*)d_ws;
  size_t off = 0;
  auto alloc = [&](size_t bytes) {
    void* p = ws + off;
    off += (bytes + 255) & ~(size_t)255;
    return p;
  };
  half_t* A1hi = (half_t*)alloc((size_t)TB * NTOKP * 2);
  half_t* A1lo = (half_t*)alloc((size_t)TB * NTOKP * 2);
  half_t* B1hi = (half_t*)alloc((size_t)NINP * NTOKP * 2);
  half_t* B1lo = (half_t*)alloc((size_t)NINP * NTOKP * 2);
  half_t* encA = (half_t*)alloc((size_t)TB * NINP * 2);
  half_t* B2 = (half_t*)alloc((size_t)NHID * NINP * 2);
  half_t* obsA = (half_t*)alloc((size_t)TB * NHID * 2);
  half_t* WBh = (half_t*)alloc((size_t)NHID * NHID * 2);
  half_t* B4 = (half_t*)alloc((size_t)2048 * NHID * 2);
  float* Vbuf = (float*)alloc((size_t)TB * NHID * 4);
  half_t* BN = (half_t*)alloc((size_t)TB * NHID * 2);
  float* bstate = (float*)alloc((size_t)BSZ * NHID * 4);
  half_t* WWT = (half_t*)alloc((size_t)NH2 * NHID * 2);
  half_t* Mmat = (half_t*)alloc((size_t)TB * NH2 * 2);
  if (off > ws_size) return;  // workspace too small: fail loudly

  // split-K partials alias the (not-yet-written) Mmat region: 4x 4MB f32
  float* Pk = (float*)Mmat;

  float* outp = (float*)d_out;
  float* bfinal = outp + (size_t)TB * NTOK;

  // conversions
  cvt_split_pad_k<<<(TB * NTOKP) / 256, 256, 0, stream>>>(input, A1hi, A1lo, NTOK);
  cvt_split_pad_k<<<(NINP * NTOKP) / 256, 256, 0, stream>>>(RBF_w, B1hi, B1lo, NTOK);
  cvt_half_k<<<(NHID * NINP) / 256, 256, 0, stream>>>(emb_w, B2, NHID * NINP);
  cvt_half_k<<<(NHID * NHID) / 256, 256, 0, stream>>>(wfef_b, WBh, NHID * NHID);
  cvt_pad_rows_k<<<(2048 * NHID) / 256, 256, 0, stream>>>(dec_w, B4, NTOK);
  permute_wfef_k<<<dim3(256, 8, 8), dim3(32, 8), 0, stream>>>(wfef_w, WWT);

  // encoded = cos(input @ RBF_w.T + RBF_b) * scale  [split precision, split-K=4]
  gemm1_splitk_k<<<512, 256, 0, stream>>>(A1hi, A1lo, B1hi, B1lo, Pk);
  rbf_combine_k<<<(TB * NINP / 4) / 256, 256, 0, stream>>>(Pk, RBF_b, encA);
  // obs = encoded @ emb_w.T + emb_b
  gemm128_k<1><<<dim3(8, 2), 256, 0, stream>>>(encA, B2, obsA, emb_b, NINP, NHID, 0);
  // V = obs @ reshape(wfef_b)^T
  gemm128_k<2><<<dim3(8, 2), 256, 0, stream>>>(obsA, WBh, Vbuf, nullptr, NHID, NHID, 0);

  // chunked: M-GEMM (t-chunk) then scan segment while chunk is L3-hot
  for (int tc = 0; tc < BPTT / TCH; tc++) {
    const int t0 = tc * TCH;
    gemm_m_k<<<2048, 256, 0, stream>>>(obsA + (size_t)t0 * 32 * NHID, WWT,
                                       Mmat + (size_t)t0 * 32 * NH2);
    scan_seg_k<<<32, 1024, 0, stream>>>(Mmat + (size_t)t0 * 32 * NH2, Vbuf, t0,
                                        (t0 == 0) ? b0 : bstate, bstate, BN, bfinal);
  }

  // outputs = BN @ dec_w.T + dec_b
  gemm128_k<3><<<dim3(8, 16), 256, 0, stream>>>(BN, B4, outp, dec_b, NHID, NTOK, NTOK);
}